// Round 19
// baseline (253.616 us; speedup 1.0000x reference)
//
#include <hip/hip_runtime.h>
#include <hip/hip_bf16.h>
#include <cstdint>
#include <cstddef>

// Problem constants (shapes fixed by the reference)
#define NN      10000      // nodes (M == N == 10000)
#define DD      256        // feature dim
#define KSTEPS  313        // ceil(10016/32) K-steps of 32
#define MB2     79         // ceil(10000/128) m-blocks for big GEMM (BM=128)
#define KSPLIT  6          // 79*6 = 474 blocks, 2/CU

typedef __bf16 bf16x8 __attribute__((ext_vector_type(8)));
typedef float  f32x4  __attribute__((ext_vector_type(4)));

// ---- workspace layout (bytes) ----
#define XG_OFF   0ull
#define XG_SIZE  (32ull * 10000 * 16)        // [q=kb*4+g][row] 16B chunks (bf16 X, MFMA-A layout)
#define WG_OFF   (XG_OFF + XG_SIZE)
#define WG_SIZE  (32ull * 256 * 16)          // [q][n] chunks (bf16 W, MFMA-B layout)
#define YG_OFF   (WG_OFF + WG_SIZE)
#define YG_SIZE  (318ull * 1088 * 16)        // [kb32][chunk]; kb 312..317 zeroed by k_prep first
#define PN_OFF   (YG_OFF + YG_SIZE)
#define PN_SIZE  ((size_t)KSPLIT * 10000 * 272 * 4)  // per-kc partials: 256 numer cols + den at col 256
#define CNT_OFF  (PN_OFF + PN_SIZE)
#define CNT_SIZE (256ull)                    // 79 uints: per-mb arrival counters (zeroed by k_prep)

// async global(16B) -> LDS copy; dest = wave-uniform base + lane*16
__device__ __forceinline__ void gl_lds16(const void* g, void* lds) {
    __builtin_amdgcn_global_load_lds(
        (const __attribute__((address_space(1))) unsigned int*)g,
        (__attribute__((address_space(3))) unsigned int*)lds,
        16, 0, 0);
}

// ---------------- K0: build XG + WG, zero YG pads + cnt (fused prep) ----------------
// blocks 0..1249: XG; 1250..1281: WG; 1282: zero YG kb312..317 + cnt
__global__ __launch_bounds__(256) void k_prep(const float* __restrict__ X,
                                              bf16x8* __restrict__ XG,
                                              const float* __restrict__ W,
                                              bf16x8* __restrict__ WG,
                                              bf16x8* __restrict__ YG,
                                              unsigned int* __restrict__ cnt) {
    int b = blockIdx.x;
    if (b < 1250) {
        int idx = b * 256 + threadIdx.x;   // 0..319999
        int row = idx >> 5;
        int q   = idx & 31;
        const float* src = X + row * 256 + q * 8;
        bf16x8 v;
#pragma unroll
        for (int j = 0; j < 8; ++j) v[j] = (__bf16)src[j];
        XG[q * 10000 + row] = v;
    } else if (b < 1282) {
        int e = (b - 1250) * 256 + threadIdx.x;   // 0..8191
        int q = e >> 8;
        int n = e & 255;
        bf16x8 v;
#pragma unroll
        for (int j = 0; j < 8; ++j) v[j] = (__bf16)W[(q * 8 + j) * 256 + n];
        WG[e] = v;
    } else {
        bf16x8 z;
#pragma unroll
        for (int j = 0; j < 8; ++j) z[j] = (__bf16)0.0f;
        for (int c = threadIdx.x; c < 6 * 1088; c += 256)
            YG[312 * 1088 + c] = z;
        if (threadIdx.x < MB2) cnt[threadIdx.x] = 0u;
    }
}

// ---------------- K1: X@W (MFMA) + tanh/e/hsum + g=exp(e) + COALESCED Y-build (fused) ----------------
// (R18 kernel verbatim — inp never touches global; coalesced 16-B YG chunk emit.)
__global__ __launch_bounds__(256) void k_gemm1(const bf16x8* __restrict__ XG,
                                               const bf16x8* __restrict__ WG,
                                               const float* __restrict__ bvec,
                                               const float* __restrict__ avec,
                                               bf16x8* __restrict__ YG) {
    __shared__ union {
        struct { bf16x8 A[320]; bf16x8 B[1024]; } st;   // 21504 B (staging)
        __bf16 Y[80][266];                              // 42560 B (epilogue; stride 266 spreads banks)
    } u;
    __shared__ float ePart[4][80];
    __shared__ float hPart[4][80];
    __shared__ float gsh[80];
    int tid = threadIdx.x, wid = tid >> 6, lane = tid & 63;
    int l15 = lane & 15, l4 = lane >> 4;
    int mb = blockIdx.x;

    f32x4 acc[4][5];
#pragma unroll
    for (int c = 0; c < 4; ++c)
#pragma unroll
        for (int rt = 0; rt < 5; ++rt) acc[c][rt] = f32x4{0.f, 0.f, 0.f, 0.f};

    for (int kb = 0; kb < 8; ++kb) {
        for (int rr = wid; rr < 5; rr += 4) {
            int c = rr * 64 + lane;
            int g = c / 80, r = c - g * 80;
            gl_lds16(XG + ((kb * 4 + g) * 10000 + mb * 80 + r), (char*)u.st.A + rr * 1024);
        }
        for (int rr = wid; rr < 16; rr += 4)
            gl_lds16(WG + kb * 1024 + rr * 64 + lane, (char*)u.st.B + rr * 1024);
        __syncthreads();

        bf16x8 af[5];
#pragma unroll
        for (int rt = 0; rt < 5; ++rt) af[rt] = u.st.A[l4 * 80 + rt * 16 + l15];
#pragma unroll
        for (int c = 0; c < 4; ++c) {
            bf16x8 bf = u.st.B[l4 * 256 + (wid * 4 + c) * 16 + l15];
#pragma unroll
            for (int rt = 0; rt < 5; ++rt)
                acc[c][rt] = __builtin_amdgcn_mfma_f32_16x16x32_bf16(af[rt], bf, acc[c][rt], 0, 0, 0);
        }
        __syncthreads();
    }

    float pe[5][4], ph[5][4];
#pragma unroll
    for (int rt = 0; rt < 5; ++rt)
#pragma unroll
        for (int rg = 0; rg < 4; ++rg) { pe[rt][rg] = 0.f; ph[rt][rg] = 0.f; }

#pragma unroll
    for (int c = 0; c < 4; ++c) {
        int col = (wid * 4 + c) * 16 + l15;
        float av = avec[col];
        float bv = bvec[col];
#pragma unroll
        for (int rt = 0; rt < 5; ++rt) {
#pragma unroll
            for (int rg = 0; rg < 4; ++rg) {
                float h = tanhf(acc[c][rt][rg] + bv);   // inp excludes bias (per reference)
                pe[rt][rg] += h * av;
                ph[rt][rg] += h;
            }
        }
    }
#pragma unroll
    for (int rt = 0; rt < 5; ++rt) {
#pragma unroll
        for (int rg = 0; rg < 4; ++rg) {
            float se = pe[rt][rg], sh = ph[rt][rg];
#pragma unroll
            for (int m = 1; m < 16; m <<= 1) {
                se += __shfl_xor(se, m);
                sh += __shfl_xor(sh, m);
            }
            if (l15 == 0) {
                int lr = rt * 16 + l4 * 4 + rg;   // 0..79
                ePart[wid][lr] = se;
                hPart[wid][lr] = sh;
            }
        }
    }
    __syncthreads();
    if (tid < 80) {
        float e = ePart[0][tid] + ePart[1][tid] + ePart[2][tid] + ePart[3][tid];
        float h = hPart[0][tid] + hPart[1][tid] + hPart[2][tid] + hPart[3][tid];
        gsh[tid] = (h != 0.0f) ? expf(e) : 0.0f;   // valid-mask fused into g
    }
    __syncthreads();   // gsh visible; staging reads done -> safe to reuse union

#pragma unroll
    for (int c = 0; c < 4; ++c) {
        int col = (wid * 4 + c) * 16 + l15;
#pragma unroll
        for (int rt = 0; rt < 5; ++rt) {
#pragma unroll
            for (int rg = 0; rg < 4; ++rg) {
                int rl = rt * 16 + l4 * 4 + rg;   // 0..79
                u.Y[rl][col] = (__bf16)(gsh[rl] * acc[c][rt][rg]);
            }
        }
    }
    if (tid < 80) u.Y[tid][256] = (__bf16)gsh[tid];
    __syncthreads();

    for (int cc = tid; cc < 2570; cc += 256) {
        int rg8 = cc / 257, col = cc - rg8 * 257;
        int row0 = mb * 80 + rg8 * 8;
        int kb = row0 >> 5, oct = (row0 >> 3) & 3;
        bf16x8 v;
#pragma unroll
        for (int j = 0; j < 8; ++j) v[j] = u.Y[rg8 * 8 + j][col];
        YG[kb * 1088 + oct * 272 + col] = v;
    }
}

// ---- int32 {0,1} pair-of-int4 -> bf16x8 {0,1} fragment ----
__device__ __forceinline__ bf16x8 cvt_adj(int4 a, int4 b) {
    union { bf16x8 v; unsigned int u[4]; } r;
    r.u[0] = (a.x > 0 ? 0x3F80u : 0u) | (a.y > 0 ? 0x3F800000u : 0u);
    r.u[1] = (a.z > 0 ? 0x3F80u : 0u) | (a.w > 0 ? 0x3F800000u : 0u);
    r.u[2] = (b.x > 0 ? 0x3F80u : 0u) | (b.y > 0 ? 0x3F800000u : 0u);
    r.u[3] = (b.z > 0 ? 0x3F80u : 0u) | (b.w > 0 ? 0x3F800000u : 0u);
    return r.v;
}

// ---------------- K4: num_kc = adj @ Y (R11 loop verbatim) + LAST-BLOCK fused finalize ----------------
// After storing partials: device-scope release fence + atomicAdd(cnt[mb]). The 6th
// arrival re-reads the 6 partials (L3-warm, first-touch for this block -> no stale L2)
// and writes out directly. Reduction order is a fixed kc loop -> deterministic output.
__global__ __launch_bounds__(256, 2) void k_attn_gemm(const int* __restrict__ adj,
                                                      const bf16x8* __restrict__ YG,
                                                      float* __restrict__ pnum,
                                                      unsigned int* __restrict__ cnt,
                                                      float* __restrict__ out) {
    __shared__ int    Ash[2][4096];   // [buf][row*32 + k'] ints: 2 x 16 KB (swizzled 16B chunks)
    __shared__ bf16x8 Bsh[2][1088];   // [buf] 32x272 bf16 tiles: 2 x 17 KB
    __shared__ unsigned int sOld;
    int tid = threadIdx.x, wid = tid >> 6, lane = tid & 63;
    int l15 = lane & 15, l4 = lane >> 4;

    // bijective kc-major XCD swizzle (m204): 474 = 8*59 + 2; <=2 YG slices per XCD L2
    int orig = blockIdx.x;
    const int nwg = MB2 * KSPLIT, q = nwg >> 3, r = nwg & 7;
    int x = orig & 7, o = orig >> 3;
    int logical = (x < r ? x * (q + 1) : r * (q + 1) + (x - r) * q) + o;
    int kc = logical / MB2, mb = logical % MB2;
    int s0 = (kc * KSTEPS) / KSPLIT, s1 = ((kc + 1) * KSTEPS) / KSPLIT;

    // A staging precompute: 16 gl_lds instrs block-wide (4 per wave); LDS[row][p] =
    // global chunk (p ^ (row&7)) -> staging line-coalesced, reads conflict-free.
    const int* aSrc[4];
    int aLim[4];
#pragma unroll
    for (int i = 0; i < 4; ++i) {
        int c = (wid + i * 4) * 64 + lane;
        int row = c >> 3;
        int p = c & 7;
        int ck4 = (p ^ (row & 7)) * 4;               // global int offset within step span
        int grow = min(mb * 128 + row, NN - 1);
        aSrc[i] = adj + (size_t)grow * 10000 + ck4;
        aLim[i] = 9996 - ck4;                        // min(s*32, aLim) keeps all reads in row
    }

    f32x4 acc[2][17];
#pragma unroll
    for (int t = 0; t < 2; ++t)
#pragma unroll
        for (int ct = 0; ct < 17; ++ct) acc[t][ct] = f32x4{0.f, 0.f, 0.f, 0.f};

    auto stageA = [&](int sTile, int bufIdx) {
        int kk = sTile * 32;
        char* dst = (char*)&Ash[bufIdx][0];
#pragma unroll
        for (int i = 0; i < 4; ++i)
            gl_lds16(aSrc[i] + min(kk, aLim[i]), dst + (wid + i * 4) * 1024);
    };
    auto stageB = [&](int sTile, int bufIdx) {
        const bf16x8* src = YG + (size_t)sTile * 1088;
        char* dst = (char*)&Bsh[bufIdx][0];
#pragma unroll
        for (int i = 0; i < 5; ++i) {
            int rr = wid + i * 4;
            if (rr < 17) gl_lds16(src + rr * 64 + lane, dst + rr * 1024);  // wave0: 5, others: 4
        }
    };

    // A-frag read offsets (swizzled): row = wid*32 + rt*16 + l15 (row&7 == l15&7)
    int xr = l15 & 7;
    int p0 = (2 * l4) ^ xr;                 // LDS chunk holding global chunk 2*l4
    int rowA0 = wid * 32 + l15;             // rt=0 row; rt=1 adds 16 (doesn't change &7)

    // ---- prologue ----
    stageA(s0, 0);
    stageB(s0, 0);
    __syncthreads();

    // ---- main loop: one barrier per step, everything async ----
    int buf = 0;
    for (int s = s0; s < s1; ++s) {
        if (s + 1 < s1) {
            stageA(s + 1, buf ^ 1);
            stageB(s + 1, buf ^ 1);
        }
        const int* ab = &Ash[buf][0];
        int4 v00 = *(const int4*)(ab + rowA0 * 32 + p0 * 4);
        int4 v01 = *(const int4*)(ab + rowA0 * 32 + (p0 ^ 1) * 4);
        int4 v10 = *(const int4*)(ab + (rowA0 + 16) * 32 + p0 * 4);
        int4 v11 = *(const int4*)(ab + (rowA0 + 16) * 32 + (p0 ^ 1) * 4);
        bf16x8 fa0 = cvt_adj(v00, v01);
        bf16x8 fa1 = cvt_adj(v10, v11);
#pragma unroll
        for (int ct = 0; ct < 17; ++ct) {
            bf16x8 fb = Bsh[buf][l4 * 272 + ct * 16 + l15];
            acc[0][ct] = __builtin_amdgcn_mfma_f32_16x16x32_bf16(fa0, fb, acc[0][ct], 0, 0, 0);
            acc[1][ct] = __builtin_amdgcn_mfma_f32_16x16x32_bf16(fa1, fb, acc[1][ct], 0, 0, 0);
        }
        __syncthreads();
        buf ^= 1;
    }

    // ---- epilogue: store partials (cols 0..256; 257-271 are never read) ----
    float* base = pnum + (size_t)kc * 10000 * 272;
    int r0 = mb * 128 + wid * 32;
#pragma unroll
    for (int t = 0; t < 2; ++t) {
#pragma unroll
        for (int ct = 0; ct < 17; ++ct) {
            int col = ct * 16 + l15;
            if (col <= 256) {
#pragma unroll
                for (int rg = 0; rg < 4; ++rg) {
                    int row = r0 + t * 16 + l4 * 4 + rg;
                    if (row < NN) base[(size_t)row * 272 + col] = acc[t][ct][rg];
                }
            }
        }
    }

    // ---- last-block-done fused finalize ----
    __threadfence();                               // release: partials visible device-wide
    if (tid == 0) sOld = atomicAdd(&cnt[mb], 1u);
    __syncthreads();
    if (sOld == KSPLIT - 1) {
        __threadfence();                           // acquire side
        int rbase = mb * 128;
        for (int cell = tid; cell < 128 * 64; cell += 256) {
            int rr = cell >> 6, qq = cell & 63;
            int row = rbase + rr;
            if (row < NN) {
                float4 sv = {0.f, 0.f, 0.f, 0.f};
                float den = 0.f;
#pragma unroll
                for (int k2 = 0; k2 < KSPLIT; ++k2) {
                    const float* rowp = pnum + ((size_t)k2 * 10000 + row) * 272;
                    float4 v = ((const float4*)rowp)[qq];
                    sv.x += v.x; sv.y += v.y; sv.z += v.z; sv.w += v.w;
                    den += rowp[256];
                }
                float rs = 1.0f / fmaxf(den, 1e-30f);
                float4 o2;
                o2.x = sv.x * rs; o2.y = sv.y * rs; o2.z = sv.z * rs; o2.w = sv.w * rs;
                ((float4*)(out + (size_t)row * 256))[qq] = o2;
            }
        }
    }
}

extern "C" void kernel_launch(void* const* d_in, const int* in_sizes, int n_in,
                              void* d_out, int out_size, void* d_ws, size_t ws_size,
                              hipStream_t stream) {
    const float* X    = (const float*)d_in[0];
    const int*   adj  = (const int*)d_in[1];
    const float* W    = (const float*)d_in[3];
    const float* bvec = (const float*)d_in[4];
    const float* avec = (const float*)d_in[5];
    float* out = (float*)d_out;

    char* ws = (char*)d_ws;
    bf16x8* XG   = (bf16x8*)(ws + XG_OFF);
    bf16x8* WG   = (bf16x8*)(ws + WG_OFF);
    bf16x8* YG   = (bf16x8*)(ws + YG_OFF);
    float*  pnum = (float*)(ws + PN_OFF);
    unsigned int* cnt = (unsigned int*)(ws + CNT_OFF);

    k_prep<<<1283, 256, 0, stream>>>(X, XG, W, WG, YG, cnt);
    k_gemm1<<<125, 256, 0, stream>>>(XG, WG, bvec, avec, YG);
    k_attn_gemm<<<MB2 * KSPLIT, 256, 0, stream>>>(adj, YG, pnum, cnt, out);
}

// Round 20
// 158.572 us; speedup vs baseline: 1.5994x; 1.5994x over previous
//
#include <hip/hip_runtime.h>
#include <hip/hip_bf16.h>
#include <cstdint>
#include <cstddef>

// Problem constants (shapes fixed by the reference)
#define NN      10000      // nodes (M == N == 10000)
#define DD      256        // feature dim
#define KSTEPS  313        // ceil(10016/32) K-steps of 32
#define MB2     79         // ceil(10000/128) m-blocks for big GEMM (BM=128)
#define KSPLIT  6          // 79*6 = 474 blocks, 2/CU

typedef __bf16 bf16x8 __attribute__((ext_vector_type(8)));
typedef float  f32x4  __attribute__((ext_vector_type(4)));

// ---- workspace layout (bytes) ----
#define XG_OFF   0ull
#define XG_SIZE  (32ull * 10000 * 16)        // [q=kb*4+g][row] 16B chunks (bf16 X, MFMA-A layout)
#define WG_OFF   (XG_OFF + XG_SIZE)
#define WG_SIZE  (32ull * 256 * 16)          // [q][n] chunks (bf16 W, MFMA-B layout)
#define YG_OFF   (WG_OFF + WG_SIZE)
#define YG_SIZE  (318ull * 1088 * 16)        // [kb32][chunk]; kb 312..317 zeroed by k_prep first
#define PN_OFF   (YG_OFF + YG_SIZE)
#define PN_SIZE  ((size_t)KSPLIT * 10000 * 272 * 4)  // per-kc partials: 256 numer cols + den at col 256

// async global(16B) -> LDS copy; dest = wave-uniform base + lane*16
__device__ __forceinline__ void gl_lds16(const void* g, void* lds) {
    __builtin_amdgcn_global_load_lds(
        (const __attribute__((address_space(1))) unsigned int*)g,
        (__attribute__((address_space(3))) unsigned int*)lds,
        16, 0, 0);
}

// ---------------- K0: build XG + WG, zero YG kb 312..317 (fused prep) ----------------
__global__ __launch_bounds__(256) void k_prep(const float* __restrict__ X,
                                              bf16x8* __restrict__ XG,
                                              const float* __restrict__ W,
                                              bf16x8* __restrict__ WG,
                                              bf16x8* __restrict__ YG) {
    int b = blockIdx.x;
    if (b < 1250) {
        int idx = b * 256 + threadIdx.x;   // 0..319999
        int row = idx >> 5;
        int q   = idx & 31;
        const float* src = X + row * 256 + q * 8;
        bf16x8 v;
#pragma unroll
        for (int j = 0; j < 8; ++j) v[j] = (__bf16)src[j];
        XG[q * 10000 + row] = v;
    } else if (b < 1282) {
        int e = (b - 1250) * 256 + threadIdx.x;   // 0..8191
        int q = e >> 8;
        int n = e & 255;
        bf16x8 v;
#pragma unroll
        for (int j = 0; j < 8; ++j) v[j] = (__bf16)W[(q * 8 + j) * 256 + n];
        WG[e] = v;
    } else {
        bf16x8 z;
#pragma unroll
        for (int j = 0; j < 8; ++j) z[j] = (__bf16)0.0f;
        for (int c = threadIdx.x; c < 6 * 1088; c += 256)
            YG[312 * 1088 + c] = z;
    }
}

// ---------------- K1: X@W (MFMA) + tanh/e/hsum + g=exp(e) + COALESCED Y-build (fused) ----------------
// Block mb owns rows mb*80..+79. inp never touches global memory: acc stays in regs,
// Y = g*inp staged as bf16 in LDS (union-overlaid on the staging buffers), then
// emitted as 16-B YG chunks via coalesced global_store_dwordx4.
// No gmax (validated R16/R17: |e|<~6, softmax scale-invariant, absmax unchanged).
__global__ __launch_bounds__(256) void k_gemm1(const bf16x8* __restrict__ XG,
                                               const bf16x8* __restrict__ WG,
                                               const float* __restrict__ bvec,
                                               const float* __restrict__ avec,
                                               bf16x8* __restrict__ YG) {
    __shared__ union {
        struct { bf16x8 A[320]; bf16x8 B[1024]; } st;   // 21504 B (staging)
        __bf16 Y[80][266];                              // 42560 B (epilogue; stride 266 spreads banks)
    } u;
    __shared__ float ePart[4][80];
    __shared__ float hPart[4][80];
    __shared__ float gsh[80];
    int tid = threadIdx.x, wid = tid >> 6, lane = tid & 63;
    int l15 = lane & 15, l4 = lane >> 4;
    int mb = blockIdx.x;

    f32x4 acc[4][5];
#pragma unroll
    for (int c = 0; c < 4; ++c)
#pragma unroll
        for (int rt = 0; rt < 5; ++rt) acc[c][rt] = f32x4{0.f, 0.f, 0.f, 0.f};

    for (int kb = 0; kb < 8; ++kb) {
        for (int rr = wid; rr < 5; rr += 4) {
            int c = rr * 64 + lane;
            int g = c / 80, r = c - g * 80;
            gl_lds16(XG + ((kb * 4 + g) * 10000 + mb * 80 + r), (char*)u.st.A + rr * 1024);
        }
        for (int rr = wid; rr < 16; rr += 4)
            gl_lds16(WG + kb * 1024 + rr * 64 + lane, (char*)u.st.B + rr * 1024);
        __syncthreads();

        bf16x8 af[5];
#pragma unroll
        for (int rt = 0; rt < 5; ++rt) af[rt] = u.st.A[l4 * 80 + rt * 16 + l15];
#pragma unroll
        for (int c = 0; c < 4; ++c) {
            bf16x8 bf = u.st.B[l4 * 256 + (wid * 4 + c) * 16 + l15];
#pragma unroll
            for (int rt = 0; rt < 5; ++rt)
                acc[c][rt] = __builtin_amdgcn_mfma_f32_16x16x32_bf16(af[rt], bf, acc[c][rt], 0, 0, 0);
        }
        __syncthreads();
    }

    // per-thread partial e (h@a) and hsum; inp kept in acc registers
    float pe[5][4], ph[5][4];
#pragma unroll
    for (int rt = 0; rt < 5; ++rt)
#pragma unroll
        for (int rg = 0; rg < 4; ++rg) { pe[rt][rg] = 0.f; ph[rt][rg] = 0.f; }

#pragma unroll
    for (int c = 0; c < 4; ++c) {
        int col = (wid * 4 + c) * 16 + l15;
        float av = avec[col];
        float bv = bvec[col];
#pragma unroll
        for (int rt = 0; rt < 5; ++rt) {
#pragma unroll
            for (int rg = 0; rg < 4; ++rg) {
                float h = tanhf(acc[c][rt][rg] + bv);   // inp excludes bias (per reference)
                pe[rt][rg] += h * av;
                ph[rt][rg] += h;
            }
        }
    }
#pragma unroll
    for (int rt = 0; rt < 5; ++rt) {
#pragma unroll
        for (int rg = 0; rg < 4; ++rg) {
            float se = pe[rt][rg], sh = ph[rt][rg];
#pragma unroll
            for (int m = 1; m < 16; m <<= 1) {
                se += __shfl_xor(se, m);
                sh += __shfl_xor(sh, m);
            }
            if (l15 == 0) {
                int lr = rt * 16 + l4 * 4 + rg;   // 0..79
                ePart[wid][lr] = se;
                hPart[wid][lr] = sh;
            }
        }
    }
    __syncthreads();
    if (tid < 80) {
        float e = ePart[0][tid] + ePart[1][tid] + ePart[2][tid] + ePart[3][tid];
        float h = hPart[0][tid] + hPart[1][tid] + hPart[2][tid] + hPart[3][tid];
        gsh[tid] = (h != 0.0f) ? expf(e) : 0.0f;   // valid-mask fused into g
    }
    __syncthreads();   // gsh visible; staging reads done -> safe to reuse union

    // stage Y = g*inp into LDS (bf16), den column 256 = g
#pragma unroll
    for (int c = 0; c < 4; ++c) {
        int col = (wid * 4 + c) * 16 + l15;
#pragma unroll
        for (int rt = 0; rt < 5; ++rt) {
#pragma unroll
            for (int rg = 0; rg < 4; ++rg) {
                int rl = rt * 16 + l4 * 4 + rg;   // 0..79
                u.Y[rl][col] = (__bf16)(gsh[rl] * acc[c][rt][rg]);
            }
        }
    }
    if (tid < 80) u.Y[tid][256] = (__bf16)gsh[tid];
    __syncthreads();

    // emit 16-B chunks: 10 row-groups x 257 cols; chunk = 8 rows of one col
    for (int cc = tid; cc < 2570; cc += 256) {
        int rg8 = cc / 257, col = cc - rg8 * 257;
        int row0 = mb * 80 + rg8 * 8;
        int kb = row0 >> 5, oct = (row0 >> 3) & 3;
        bf16x8 v;
#pragma unroll
        for (int j = 0; j < 8; ++j) v[j] = u.Y[rg8 * 8 + j][col];
        YG[kb * 1088 + oct * 272 + col] = v;
    }
}

// ---- int32 {0,1} pair-of-int4 -> bf16x8 {0,1} fragment ----
__device__ __forceinline__ bf16x8 cvt_adj(int4 a, int4 b) {
    union { bf16x8 v; unsigned int u[4]; } r;
    r.u[0] = (a.x > 0 ? 0x3F80u : 0u) | (a.y > 0 ? 0x3F800000u : 0u);
    r.u[1] = (a.z > 0 ? 0x3F80u : 0u) | (a.w > 0 ? 0x3F800000u : 0u);
    r.u[2] = (b.x > 0 ? 0x3F80u : 0u) | (b.y > 0 ? 0x3F800000u : 0u);
    r.u[3] = (b.z > 0 ? 0x3F80u : 0u) | (b.w > 0 ? 0x3F800000u : 0u);
    return r.v;
}

// ---------------- K4: num_kc = adj @ Y  (R11 all-async kernel, verbatim — best measured) ----------------
__global__ __launch_bounds__(256, 2) void k_attn_gemm(const int* __restrict__ adj,
                                                      const bf16x8* __restrict__ YG,
                                                      float* __restrict__ pnum) {
    __shared__ int    Ash[2][4096];   // [buf][row*32 + k'] ints: 2 x 16 KB (swizzled 16B chunks)
    __shared__ bf16x8 Bsh[2][1088];   // [buf] 32x272 bf16 tiles: 2 x 17 KB
    int tid = threadIdx.x, wid = tid >> 6, lane = tid & 63;
    int l15 = lane & 15, l4 = lane >> 4;

    // bijective kc-major XCD swizzle (m204): 474 = 8*59 + 2; <=2 YG slices per XCD L2
    int orig = blockIdx.x;
    const int nwg = MB2 * KSPLIT, q = nwg >> 3, r = nwg & 7;
    int x = orig & 7, o = orig >> 3;
    int logical = (x < r ? x * (q + 1) : r * (q + 1) + (x - r) * q) + o;
    int kc = logical / MB2, mb = logical % MB2;
    int s0 = (kc * KSTEPS) / KSPLIT, s1 = ((kc + 1) * KSTEPS) / KSPLIT;

    // A staging precompute: 16 gl_lds instrs block-wide (4 per wave); LDS[row][p] =
    // global chunk (p ^ (row&7)) -> staging line-coalesced, reads conflict-free.
    const int* aSrc[4];
    int aLim[4];
#pragma unroll
    for (int i = 0; i < 4; ++i) {
        int c = (wid + i * 4) * 64 + lane;
        int row = c >> 3;
        int p = c & 7;
        int ck4 = (p ^ (row & 7)) * 4;               // global int offset within step span
        int grow = min(mb * 128 + row, NN - 1);
        aSrc[i] = adj + (size_t)grow * 10000 + ck4;
        aLim[i] = 9996 - ck4;                        // min(s*32, aLim) keeps all reads in row
    }

    f32x4 acc[2][17];
#pragma unroll
    for (int t = 0; t < 2; ++t)
#pragma unroll
        for (int ct = 0; ct < 17; ++ct) acc[t][ct] = f32x4{0.f, 0.f, 0.f, 0.f};

    auto stageA = [&](int sTile, int bufIdx) {
        int kk = sTile * 32;
        char* dst = (char*)&Ash[bufIdx][0];
#pragma unroll
        for (int i = 0; i < 4; ++i)
            gl_lds16(aSrc[i] + min(kk, aLim[i]), dst + (wid + i * 4) * 1024);
    };
    auto stageB = [&](int sTile, int bufIdx) {
        const bf16x8* src = YG + (size_t)sTile * 1088;
        char* dst = (char*)&Bsh[bufIdx][0];
#pragma unroll
        for (int i = 0; i < 5; ++i) {
            int rr = wid + i * 4;
            if (rr < 17) gl_lds16(src + rr * 64 + lane, dst + rr * 1024);  // wave0: 5, others: 4
        }
    };

    // A-frag read offsets (swizzled): row = wid*32 + rt*16 + l15 (row&7 == l15&7)
    int xr = l15 & 7;
    int p0 = (2 * l4) ^ xr;                 // LDS chunk holding global chunk 2*l4
    int rowA0 = wid * 32 + l15;             // rt=0 row; rt=1 adds 16 (doesn't change &7)

    // ---- prologue ----
    stageA(s0, 0);
    stageB(s0, 0);
    __syncthreads();

    // ---- main loop: one barrier per step, everything async ----
    int buf = 0;
    for (int s = s0; s < s1; ++s) {
        if (s + 1 < s1) {
            stageA(s + 1, buf ^ 1);
            stageB(s + 1, buf ^ 1);
        }
        const int* ab = &Ash[buf][0];
        int4 v00 = *(const int4*)(ab + rowA0 * 32 + p0 * 4);
        int4 v01 = *(const int4*)(ab + rowA0 * 32 + (p0 ^ 1) * 4);
        int4 v10 = *(const int4*)(ab + (rowA0 + 16) * 32 + p0 * 4);
        int4 v11 = *(const int4*)(ab + (rowA0 + 16) * 32 + (p0 ^ 1) * 4);
        bf16x8 fa0 = cvt_adj(v00, v01);
        bf16x8 fa1 = cvt_adj(v10, v11);
#pragma unroll
        for (int ct = 0; ct < 17; ++ct) {
            bf16x8 fb = Bsh[buf][l4 * 272 + ct * 16 + l15];
            acc[0][ct] = __builtin_amdgcn_mfma_f32_16x16x32_bf16(fa0, fb, acc[0][ct], 0, 0, 0);
            acc[1][ct] = __builtin_amdgcn_mfma_f32_16x16x32_bf16(fa1, fb, acc[1][ct], 0, 0, 0);
        }
        __syncthreads();
        buf ^= 1;
    }

    // ---- epilogue: plain stores to per-kc partial buffer (cols 0..256; 257-271 dead) ----
    float* base = pnum + (size_t)kc * 10000 * 272;
    int r0 = mb * 128 + wid * 32;
#pragma unroll
    for (int t = 0; t < 2; ++t) {
#pragma unroll
        for (int ct = 0; ct < 17; ++ct) {
            int col = ct * 16 + l15;
            if (col <= 256) {
#pragma unroll
                for (int rg = 0; rg < 4; ++rg) {
                    int row = r0 + t * 16 + l4 * 4 + rg;
                    if (row < NN) base[(size_t)row * 272 + col] = acc[t][ct][rg];
                }
            }
        }
    }
}

// ---------------- K5: out = (sum_kc num_kc) / max(sum_kc den_kc, 1e-30) ----------------
__global__ __launch_bounds__(256) void k_finalize(const float* __restrict__ pnum,
                                                  float* __restrict__ out) {
    int idx = blockIdx.x * 256 + threadIdx.x;   // 0..639999 (float4 units)
    int i = idx >> 6, q = idx & 63;
    float4 sv = {0.f, 0.f, 0.f, 0.f};
    float den = 0.f;
#pragma unroll
    for (int kc = 0; kc < KSPLIT; ++kc) {
        const float* row = pnum + ((size_t)kc * 10000 + i) * 272;
        float4 v = ((const float4*)row)[q];
        sv.x += v.x; sv.y += v.y; sv.z += v.z; sv.w += v.w;
        den += row[256];
    }
    float r = 1.0f / fmaxf(den, 1e-30f);
    float4 o;
    o.x = sv.x * r; o.y = sv.y * r; o.z = sv.z * r; o.w = sv.w * r;
    ((float4*)(out + (size_t)i * 256))[q] = o;
}

extern "C" void kernel_launch(void* const* d_in, const int* in_sizes, int n_in,
                              void* d_out, int out_size, void* d_ws, size_t ws_size,
                              hipStream_t stream) {
    const float* X    = (const float*)d_in[0];
    const int*   adj  = (const int*)d_in[1];
    const float* W    = (const float*)d_in[3];
    const float* bvec = (const float*)d_in[4];
    const float* avec = (const float*)d_in[5];
    float* out = (float*)d_out;

    char* ws = (char*)d_ws;
    bf16x8* XG   = (bf16x8*)(ws + XG_OFF);
    bf16x8* WG   = (bf16x8*)(ws + WG_OFF);
    bf16x8* YG   = (bf16x8*)(ws + YG_OFF);
    float*  pnum = (float*)(ws + PN_OFF);

    k_prep<<<1283, 256, 0, stream>>>(X, XG, W, WG, YG);
    k_gemm1<<<125, 256, 0, stream>>>(XG, WG, bvec, avec, YG);
    k_attn_gemm<<<MB2 * KSPLIT, 256, 0, stream>>>(adj, YG, pnum);
    k_finalize<<<2500, 256, 0, stream>>>(pnum, out);
}